// Round 10
// baseline (70.949 us; speedup 1.0000x reference)
//
#include <hip/hip_runtime.h>
#include <hip/hip_bf16.h>

typedef float f32x4 __attribute__((ext_vector_type(4)));
typedef __bf16 bf16x8 __attribute__((ext_vector_type(8)));
typedef __bf16 bf16x4 __attribute__((ext_vector_type(4)));

#define AS1 __attribute__((address_space(1)))
#define AS3 __attribute__((address_space(3)))

static constexpr int BB = 32;      // batch
static constexpr int DM = 2560;    // d_model
static constexpr int DI = 5120;    // d_inner
static constexpr int NS = 16;      // ssm state N
static constexpr int RK = 160;     // dt_rank
static constexpr int NJ = 192;     // dt_rank + 2N

__device__ __forceinline__ float sigmoidf_(float x) { return 1.f / (1.f + __expf(-x)); }
__device__ __forceinline__ float softplusf_(float x) {
    return (x > 15.f) ? x : log1pf(__expf(x));
}

__device__ __forceinline__ bf16x8 cvt8(f32x4 a, f32x4 b) {
    bf16x8 r;
    r[0] = (__bf16)a[0]; r[1] = (__bf16)a[1]; r[2] = (__bf16)a[2]; r[3] = (__bf16)a[3];
    r[4] = (__bf16)b[0]; r[5] = (__bf16)b[1]; r[6] = (__bf16)b[2]; r[7] = (__bf16)b[3];
    return r;
}

#define WAITN(N) do { asm volatile("s_waitcnt vmcnt(" #N ")" ::: "memory"); \
                      __builtin_amdgcn_sched_barrier(0); } while (0)

// Opaque VGPR-path 16B load (deep HW queues; compiler cannot sink/merge).
#define GLDP(dst, ptr) \
    asm volatile("global_load_dwordx4 %0, %1, off" : "=v"(dst) : "v"(ptr) : "memory")

// Non-temporal helpers: single-use traffic must not evict L3-resident weights.
__device__ __forceinline__ float ntldf(const float* p) { return __builtin_nontemporal_load(p); }
__device__ __forceinline__ f32x4 ntld4(const float* p) {
    return __builtin_nontemporal_load((const f32x4*)p);
}
__device__ __forceinline__ void ntst4(float* p, f32x4 v) {
    __builtin_nontemporal_store(v, (f32x4*)p);
}

// ---------------------------------------------------------------------------
// Reg-staged burst GEMM (R9 structure, unchanged except nt partial stores):
// 32 d x 32 b tile, K-slice 256. Lane l loads 16B chunk l of one CONTIGUOUS
// 1KB row (perfect coalescing, VGPR path), vmcnt(0), ds_write into padded-
// slab LDS, one barrier, 8 MFMA/wave. 3 blocks/CU overlap across blocks.
// Split-K partials to disjoint buffers; consumer reduces (nt both sides).
// ---------------------------------------------------------------------------
__global__ __launch_bounds__(256, 3) void gemmrs(
    const float* __restrict__ W0, float* __restrict__ C0,
    const float* __restrict__ W1, float* __restrict__ C1,
    const __bf16* __restrict__ Xh,
    int K, int ldc, int nm, int S, int cstride)
{
    __shared__ float  Ws[32 * 260];     // 32 rows x 1040B slab
    __shared__ __bf16 Xs[16 * 520];     // 16 slabs (2 rows) x 1040B

    int bid = blockIdx.x;
    int m = bid % nm;
    int rest = bid / nm;
    int s = rest % S;
    int mat = rest / S;
    const float* W = mat ? W1 : W0;
    float* C = (mat ? C1 : C0) + (size_t)s * cstride;

    int d0 = m * 32;
    int k0 = s * 256;

    int t = threadIdx.x, l = t & 63, w = t >> 6;

    // ---- issue all 12 staging loads (8 W rows + 4 X slabs), asm-opaque ----
    f32x4 wv0, wv1, wv2, wv3, wv4, wv5, wv6, wv7, xv0, xv1, xv2, xv3;
    {
        const float* wb = W + (size_t)(d0 + 8 * w) * K + k0 + l * 4;
        GLDP(wv0, wb);            GLDP(wv1, wb + 1 * (size_t)K);
        GLDP(wv2, wb + 2 * (size_t)K);  GLDP(wv3, wb + 3 * (size_t)K);
        GLDP(wv4, wb + 4 * (size_t)K);  GLDP(wv5, wb + 5 * (size_t)K);
        GLDP(wv6, wb + 6 * (size_t)K);  GLDP(wv7, wb + 7 * (size_t)K);
        const __bf16* xb = Xh + (size_t)(8 * w + (l >> 5)) * K + k0 + (l & 31) * 8;
        GLDP(xv0, xb);            GLDP(xv1, xb + 2 * (size_t)K);
        GLDP(xv2, xb + 4 * (size_t)K);  GLDP(xv3, xb + 6 * (size_t)K);
    }
    WAITN(0);

    // ---- LDS writes (padded slabs) ----
    *(f32x4*)&Ws[(8 * w + 0) * 260 + l * 4] = wv0;
    *(f32x4*)&Ws[(8 * w + 1) * 260 + l * 4] = wv1;
    *(f32x4*)&Ws[(8 * w + 2) * 260 + l * 4] = wv2;
    *(f32x4*)&Ws[(8 * w + 3) * 260 + l * 4] = wv3;
    *(f32x4*)&Ws[(8 * w + 4) * 260 + l * 4] = wv4;
    *(f32x4*)&Ws[(8 * w + 5) * 260 + l * 4] = wv5;
    *(f32x4*)&Ws[(8 * w + 6) * 260 + l * 4] = wv6;
    *(f32x4*)&Ws[(8 * w + 7) * 260 + l * 4] = wv7;
    *(f32x4*)((void*)&Xs[(4 * w + 0) * 520 + l * 8]) = xv0;
    *(f32x4*)((void*)&Xs[(4 * w + 1) * 520 + l * 8]) = xv1;
    *(f32x4*)((void*)&Xs[(4 * w + 2) * 520 + l * 8]) = xv2;
    *(f32x4*)((void*)&Xs[(4 * w + 3) * 520 + l * 8]) = xv3;

    __syncthreads();

    // ---- compute: wave w = quadrant (mh = d-half, nh = batch-half) ----
    int mh = w & 1, nh = w >> 1;
    int r16 = l & 15;
    int q   = l >> 4;
    int ar = mh * 16 + r16;                 // W row (d)
    int br = nh * 16 + r16;                 // X row (batch)
    const float*  wrow = &Ws[ar * 260];
    const __bf16* xrow = &Xs[(br >> 1) * 520 + (br & 1) * 256];

    f32x4 acc = {0.f, 0.f, 0.f, 0.f};

    #pragma unroll
    for (int kk = 0; kk < 8; ++kk) {
        f32x4 a0 = *(const f32x4*)&wrow[(kk * 8 + q * 2    ) * 4];
        f32x4 a1 = *(const f32x4*)&wrow[(kk * 8 + q * 2 + 1) * 4];
        bf16x8 B = *(const bf16x8*)&xrow[(kk * 4 + q) * 8];
        acc = __builtin_amdgcn_mfma_f32_16x16x32_bf16(cvt8(a0, a1), B, acc, 0, 0, 0);
    }

    // partial store: single-use -> non-temporal (don't evict weights from L3)
    ntst4(&C[(size_t)br * ldc + d0 + mh * 16 + q * 4], acc);
}

// ---------------------------------------------------------------------------
// fp32 -> bf16 cast (for x).  x read once -> nt load; x_bh re-read -> cached.
// ---------------------------------------------------------------------------
__global__ __launch_bounds__(256) void cvtx(
    const float* __restrict__ in, __bf16* __restrict__ out)
{
    int i = (blockIdx.x * 256 + threadIdx.x) * 4;
    f32x4 v = ntld4(&in[i]);
    bf16x4 o;
    o[0] = (__bf16)v[0]; o[1] = (__bf16)v[1]; o[2] = (__bf16)v[2]; o[3] = (__bf16)v[3];
    *(bf16x4*)&out[i] = o;
}

// ---------------------------------------------------------------------------
// Small-tile barrier GEMM (proven; K2 only: output D=192, fp32 X, 4 MB W).
// ---------------------------------------------------------------------------
__global__ __launch_bounds__(256) void gemm32(
    const float* __restrict__ W0, float* __restrict__ C0,
    const float* __restrict__ W1, float* __restrict__ C1,
    const float* __restrict__ X,
    int K, int ldc, int nm, int S, int ksteps, int cstride)
{
    __shared__ float Wb[2][32 * 64];
    __shared__ float Xb[2][32 * 64];

    int bid = blockIdx.x;
    int m = bid % nm;
    int rest = bid / nm;
    int s = rest % S;
    int mat = rest / S;
    const float* W = mat ? W1 : W0;
    float* C = (mat ? C1 : C0) + (size_t)s * cstride;

    int d0 = m * 32;
    int k0 = s * (K / S);

    int t  = threadIdx.x;
    int l  = t & 63;
    int wv = t >> 6;
    int lr = l >> 4;
    int lc = l & 15;

    int row0 = 8 * wv + lr;
    int row1 = row0 + 4;
    int ch0 = lc ^ (row0 & 7);
    int ch1 = lc ^ (row1 & 7);
    const float* ws0 = W + (size_t)(d0 + row0) * K + k0 + ch0 * 4;
    const float* ws1 = W + (size_t)(d0 + row1) * K + k0 + ch1 * 4;
    const float* xs0 = X + (size_t)row0 * K + k0 + ch0 * 4;
    const float* xs1 = X + (size_t)row1 * K + k0 + ch1 * 4;
    int R0 = 8 * wv * 64;
    int R1 = (8 * wv + 4) * 64;

#define STAGE(pb)  do {                                                              \
        __builtin_amdgcn_global_load_lds((const AS1 void*)ws0, (AS3 void*)&Wb[pb][R0], 16, 0, 0); \
        __builtin_amdgcn_global_load_lds((const AS1 void*)ws1, (AS3 void*)&Wb[pb][R1], 16, 0, 0); \
        __builtin_amdgcn_global_load_lds((const AS1 void*)xs0, (AS3 void*)&Xb[pb][R0], 16, 0, 0); \
        __builtin_amdgcn_global_load_lds((const AS1 void*)xs1, (AS3 void*)&Xb[pb][R1], 16, 0, 0); \
        ws0 += 64; ws1 += 64; xs0 += 64; xs1 += 64;                                  \
    } while (0)

    int mh = wv & 1, nh = wv >> 1;
    int r16 = l & 15;
    int arow = mh * 16 + r16;
    int brow = nh * 16 + r16;
    int c0 = (l >> 4) * 2;
    int wo0 = arow * 64 + ((c0    ) ^ (arow & 7)) * 4;
    int wo1 = arow * 64 + ((c0 + 1) ^ (arow & 7)) * 4;
    int wo2 = arow * 64 + ((c0 + 8) ^ (arow & 7)) * 4;
    int wo3 = arow * 64 + ((c0 + 9) ^ (arow & 7)) * 4;
    int xo0 = brow * 64 + ((c0    ) ^ (brow & 7)) * 4;
    int xo1 = brow * 64 + ((c0 + 1) ^ (brow & 7)) * 4;
    int xo2 = brow * 64 + ((c0 + 8) ^ (brow & 7)) * 4;
    int xo3 = brow * 64 + ((c0 + 9) ^ (brow & 7)) * 4;

    STAGE(0);
    STAGE(1);

    f32x4 acc = {0.f, 0.f, 0.f, 0.f};

    for (int it = 0; it < ksteps; ++it) {
        int c = it & 1;
        if (it < ksteps - 1) WAITN(4); else WAITN(0);
        __builtin_amdgcn_s_barrier();

        f32x4 a0 = *(const f32x4*)&Wb[c][wo0];
        f32x4 a1 = *(const f32x4*)&Wb[c][wo1];
        f32x4 a2 = *(const f32x4*)&Wb[c][wo2];
        f32x4 a3 = *(const f32x4*)&Wb[c][wo3];
        f32x4 b0 = *(const f32x4*)&Xb[c][xo0];
        f32x4 b1 = *(const f32x4*)&Xb[c][xo1];
        f32x4 b2 = *(const f32x4*)&Xb[c][xo2];
        f32x4 b3 = *(const f32x4*)&Xb[c][xo3];
        acc = __builtin_amdgcn_mfma_f32_16x16x32_bf16(cvt8(a0, a1), cvt8(b0, b1), acc, 0, 0, 0);
        acc = __builtin_amdgcn_mfma_f32_16x16x32_bf16(cvt8(a2, a3), cvt8(b2, b3), acc, 0, 0, 0);

        __builtin_amdgcn_s_barrier();
        if (it + 2 < ksteps) STAGE(c);
    }
#undef STAGE

    int b = brow;
    int dbase = d0 + mh * 16 + (l >> 4) * 4;
    *(f32x4*)&C[(size_t)b * ldc + dbase] = acc;
}

// ---------------------------------------------------------------------------
// Depthwise causal conv (k=4) + SiLU + reduce K1 split-K partials (S=10).
// Partials and conv_states read once -> nt loads.
// ---------------------------------------------------------------------------
__global__ __launch_bounds__(256) void convk(
    const float* __restrict__ P_xs, const float* __restrict__ P_res,
    const float* __restrict__ conv_states,
    const float* __restrict__ conv_w, const float* __restrict__ conv_b,
    float* __restrict__ conv_bd, float* __restrict__ res_bd)
{
    const size_t BD = (size_t)BB * DI;
    int d = blockIdx.x * 256 + threadIdx.x;
    int b = blockIdx.y;
    size_t o = (size_t)b * DI + d;
    float xs = 0.f, rs = 0.f;
    #pragma unroll
    for (int j = 0; j < 10; ++j) {
        xs += ntldf(&P_xs[j * BD + o]);
        rs += ntldf(&P_res[j * BD + o]);
    }
    res_bd[o] = rs;
    float v = ntldf(&conv_states[(size_t)(1 * BB + b) * DI + d]) * conv_w[0 * DI + d]
            + ntldf(&conv_states[(size_t)(2 * BB + b) * DI + d]) * conv_w[1 * DI + d]
            + ntldf(&conv_states[(size_t)(3 * BB + b) * DI + d]) * conv_w[2 * DI + d]
            + xs * conv_w[3 * DI + d] + conv_b[d];
    conv_bd[o] = v * sigmoidf_(v);
}

// ---------------------------------------------------------------------------
// Reduce K2 split-K partials (nt loads).
// ---------------------------------------------------------------------------
__global__ __launch_bounds__(256) void redx(
    const float* __restrict__ p, float* __restrict__ o, int S)
{
    int i = blockIdx.x * 256 + threadIdx.x;
    float sum = 0.f;
    for (int s = 0; s < S; ++s) sum += ntldf(&p[(size_t)s * BB * NJ + i]);
    o[i] = sum;
}

// ---------------------------------------------------------------------------
// Reduce K4 split-K partials (S=20) into d_out (nt loads).
// ---------------------------------------------------------------------------
__global__ __launch_bounds__(256) void rout(
    const float* __restrict__ p, float* __restrict__ o)
{
    const int SZ = BB * DM;
    int i = blockIdx.x * 256 + threadIdx.x;
    float s = 0.f;
    #pragma unroll
    for (int j = 0; j < 20; ++j) s += ntldf(&p[(size_t)j * SZ + i]);
    o[i] = s;
}

// ---------------------------------------------------------------------------
// Fused dt GEMV + softplus + SSM recurrence + D skip + SiLU gate -> g (bf16).
// ssm_state (10.5 MB) and A_log read once -> nt loads.
// ---------------------------------------------------------------------------
__global__ __launch_bounds__(256) void ssmk2(
    const float* __restrict__ x_db, const float* __restrict__ W_dt,
    const float* __restrict__ dt_bias, const float* __restrict__ A_log,
    const float* __restrict__ Dv, const float* __restrict__ ssm_state,
    const float* __restrict__ conv_bd, const float* __restrict__ res_bd,
    __bf16* __restrict__ g_bh)
{
    __shared__ float Wdt_s[8][164];
    __shared__ float xdb_s[BB][196];
    __shared__ float Al_s[8][NS];

    int t = threadIdx.x;
    int d0 = blockIdx.x * 8;

    for (int f = t; f < 8 * RK; f += 256)
        Wdt_s[f / RK][f % RK] = W_dt[(size_t)d0 * RK + f];
    for (int f = t; f < BB * NJ; f += 256)
        xdb_s[f / NJ][f % NJ] = x_db[f];
    if (t < 8 * NS)
        Al_s[t / NS][t % NS] = ntldf(&A_log[(size_t)(d0 + t / NS) * NS + t % NS]);
    __syncthreads();

    int b  = t & 31;
    int dl = t >> 5;
    int d  = d0 + dl;

    float acc = 0.f;
    #pragma unroll 8
    for (int k4 = 0; k4 < RK / 4; ++k4) {
        f32x4 wv = *(const f32x4*)&Wdt_s[dl][k4 * 4];
        f32x4 xv = *(const f32x4*)&xdb_s[b][k4 * 4];
        acc += wv[0] * xv[0] + wv[1] * xv[1] + wv[2] * xv[2] + wv[3] * xv[3];
    }
    float dt = softplusf_(acc + dt_bias[d]);

    size_t off = (size_t)b * DI + d;
    float cv = conv_bd[off];
    float rv = res_bd[off];
    float Dd = Dv[d];

    const float* sp = ssm_state + off * NS;
    float y = 0.f;
    #pragma unroll
    for (int q = 0; q < 4; ++q) {
        f32x4 sv = ntld4(sp + q * 4);
        #pragma unroll
        for (int j = 0; j < 4; ++j) {
            int n = q * 4 + j;
            float dA = __expf(-dt * __expf(Al_s[dl][n]));
            y += (sv[j] * dA + dt * xdb_s[b][RK + n] * cv) * xdb_s[b][RK + NS + n];
        }
    }
    y += Dd * cv;
    g_bh[off] = (__bf16)(y * (rv * sigmoidf_(rv)));
}

// ---------------------------------------------------------------------------

extern "C" void kernel_launch(void* const* d_in, const int* in_sizes, int n_in,
                              void* d_out, int out_size, void* d_ws, size_t ws_size,
                              hipStream_t stream)
{
    const float* x           = (const float*)d_in[0];
    const float* conv_states = (const float*)d_in[1];
    const float* conv_w      = (const float*)d_in[2];
    const float* conv_b      = (const float*)d_in[3];
    const float* W_ssm_in    = (const float*)d_in[4];
    const float* W_mlp       = (const float*)d_in[5];
    const float* W_out       = (const float*)d_in[6];
    const float* W_x_proj    = (const float*)d_in[7];
    const float* W_dt        = (const float*)d_in[8];
    const float* dt_bias     = (const float*)d_in[9];
    const float* A_log       = (const float*)d_in[10];
    const float* Dv          = (const float*)d_in[11];
    const float* ssm_state   = (const float*)d_in[12];

    float* out = (float*)d_out;
    float* ws  = (float*)d_ws;

    const size_t BD = (size_t)BB * DI;          // 163840
    const int S1 = 10;                          // K1 split-K (gemmrs, KS=256)
    const int S2 = 20;                          // K2 split-K (gemm32)
    const int S4 = 20;                          // K4 split-K (gemmrs, KS=256)

    float* P_res   = ws;                        // 10*BD
    float* P_xs    = ws + (size_t)S1 * BD;      // 10*BD
    float* conv_bd = ws + 2 * (size_t)S1 * BD;
    float* res_bd  = conv_bd + BD;
    float* x_db_p  = res_bd + BD;               // S2*6144
    float* x_db    = x_db_p + (size_t)S2 * BB * NJ;
    __bf16* x_bh   = (__bf16*)(x_db + BB * NJ); // BB*DM bf16
    // aliases into the dead P region (after convk):
    float*  outp   = ws;                                    // S4*BB*DM floats
    __bf16* g_bh   = (__bf16*)(ws + (size_t)S4 * BB * DM);  // BD bf16

    // x -> bf16
    cvtx<<<dim3((BB * DM) / 1024), 256, 0, stream>>>(x, x_bh);

    // K1: res/xs partials (dual matrix): K=2560, 32d-tiles, KS=256, S=10
    gemmrs<<<dim3((DI / 32) * S1 * 2), 256, 0, stream>>>(
        W_mlp, P_res, W_ssm_in, P_xs, x_bh, DM, DI, DI / 32, S1, (int)BD);

    // conv + silu + reduce K1 partials
    convk<<<dim3(DI / 256, BB), 256, 0, stream>>>(
        P_xs, P_res, conv_states, conv_w, conv_b, conv_bd, res_bd);

    // K2: x_db partials = conv @ W_x_proj.T  (K=5120, S=20, ksteps=4, BK=64)
    gemm32<<<dim3(6 * S2), 256, 0, stream>>>(
        W_x_proj, x_db_p, W_x_proj, x_db_p, conv_bd, DI, NJ, 6, S2, (DI / S2) / 64, BB * NJ);

    // reduce x_db partials
    redx<<<dim3((BB * NJ) / 256), 256, 0, stream>>>(x_db_p, x_db, S2);

    // fused dt + SSM + gate -> g (bf16)
    ssmk2<<<dim3(DI / 8), 256, 0, stream>>>(
        x_db, W_dt, dt_bias, A_log, Dv, ssm_state, conv_bd, res_bd, g_bh);

    // K4: out partials = g @ W_out.T  (K=5120, 32d-tiles, KS=256, S=20)
    gemmrs<<<dim3((DM / 32) * S4), 256, 0, stream>>>(
        W_out, outp, W_out, outp, g_bh, DI, DM, DM / 32, S4, BB * DM);

    // final reduce into d_out
    rout<<<dim3((BB * DM) / 256), 256, 0, stream>>>(outp, out);
}

// Round 11
// 64.961 us; speedup vs baseline: 1.0922x; 1.0922x over previous
//
#include <hip/hip_runtime.h>
#include <hip/hip_bf16.h>

typedef float f32x4 __attribute__((ext_vector_type(4)));
typedef __bf16 bf16x8 __attribute__((ext_vector_type(8)));
typedef __bf16 bf16x4 __attribute__((ext_vector_type(4)));

#define AS1 __attribute__((address_space(1)))
#define AS3 __attribute__((address_space(3)))

static constexpr int BB = 32;      // batch
static constexpr int DM = 2560;    // d_model
static constexpr int DI = 5120;    // d_inner
static constexpr int NS = 16;      // ssm state N
static constexpr int RK = 160;     // dt_rank
static constexpr int NJ = 192;     // dt_rank + 2N

__device__ __forceinline__ float sigmoidf_(float x) { return 1.f / (1.f + __expf(-x)); }
__device__ __forceinline__ float softplusf_(float x) {
    return (x > 15.f) ? x : log1pf(__expf(x));
}

__device__ __forceinline__ bf16x8 cvt8(f32x4 a, f32x4 b) {
    bf16x8 r;
    r[0] = (__bf16)a[0]; r[1] = (__bf16)a[1]; r[2] = (__bf16)a[2]; r[3] = (__bf16)a[3];
    r[4] = (__bf16)b[0]; r[5] = (__bf16)b[1]; r[6] = (__bf16)b[2]; r[7] = (__bf16)b[3];
    return r;
}

#define WAITN(N) do { asm volatile("s_waitcnt vmcnt(" #N ")" ::: "memory"); \
                      __builtin_amdgcn_sched_barrier(0); } while (0)

// Opaque VGPR-path 16B load (deep HW queues; compiler cannot sink/merge).
#define GLDP(dst, ptr) \
    asm volatile("global_load_dwordx4 %0, %1, off" : "=v"(dst) : "v"(ptr) : "memory")

// ---------------------------------------------------------------------------
// High-occupancy reg-staged GEMM: 32 d x 32 b tile, TWO 128-elem k-slices per
// block (k0, k0+128). LDS = 25.6 KB -> 6 blocks/CU = 24 waves/CU (2x R9).
// Per wave: all 12 slice loads issued up-front (contiguous row chunks, VGPR
// path), vmcnt(6) between slices -> rolling 6-12 loads in flight per wave.
// __launch_bounds__(256,6) pins VGPR <= 85 so occupancy holds.
// Split-K partials to disjoint buffers; consumer reduces. No atomics.
// ---------------------------------------------------------------------------
__global__ __launch_bounds__(256, 6) void gemmrs2(
    const float* __restrict__ W0, float* __restrict__ C0,
    const float* __restrict__ W1, float* __restrict__ C1,
    const __bf16* __restrict__ Xh,
    int K, int ldc, int nm, int S, int cstride)
{
    __shared__ float  Ws[32 * 132];     // 32 rows x 528B slab = 16.9 KB
    __shared__ __bf16 Xs[16 * 272];     // 16 slabs (2 rows) x 544B = 8.7 KB

    int bid = blockIdx.x;
    int m = bid % nm;
    int rest = bid / nm;
    int s = rest % S;
    int mat = rest / S;
    const float* W = mat ? W1 : W0;
    float* C = (mat ? C1 : C0) + (size_t)s * cstride;

    int d0 = m * 32;
    int k0 = s * 256;                   // two 128-slices: k0 and k0+128

    int t = threadIdx.x, l = t & 63, w = t >> 6;
    int h   = l >> 5;                   // W: half-wave row select
    int c32 = l & 31;                   // W: 16B chunk within 512B row-slice
    int xi  = l >> 4;                   // X: row select 0..3
    int xc  = l & 15;                   // X: 16B chunk within 256B row-slice

    // wave w stages W rows 8w..8w+7 (2 rows/instr) and X rows 8w..8w+7 (4/instr)
    const float*  wb = W  + (size_t)(d0 + 8 * w + h) * K + k0 + c32 * 4;
    const __bf16* xb = Xh + (size_t)(8 * w + xi) * K + k0 + xc * 8;

    // issue ALL 12 loads: slice A (6) then slice B (6) -- rolling window
    f32x4 Aw0, Aw1, Aw2, Aw3, Ax0, Ax1;
    f32x4 Bw0, Bw1, Bw2, Bw3, Bx0, Bx1;
    GLDP(Aw0, wb);                      GLDP(Aw1, wb + 2 * (size_t)K);
    GLDP(Aw2, wb + 4 * (size_t)K);      GLDP(Aw3, wb + 6 * (size_t)K);
    GLDP(Ax0, xb);                      GLDP(Ax1, xb + 4 * (size_t)K);
    GLDP(Bw0, wb + 128);                GLDP(Bw1, wb + 2 * (size_t)K + 128);
    GLDP(Bw2, wb + 4 * (size_t)K + 128);GLDP(Bw3, wb + 6 * (size_t)K + 128);
    GLDP(Bx0, xb + 128);                GLDP(Bx1, xb + 4 * (size_t)K + 128);

    // loop-invariant LDS offsets
    int wr0 = 8 * w + h;
    int wls0 = (wr0    ) * 132 + c32 * 4;
    int wls1 = (wr0 + 2) * 132 + c32 * 4;
    int wls2 = (wr0 + 4) * 132 + c32 * 4;
    int wls3 = (wr0 + 6) * 132 + c32 * 4;
    int xr0 = 8 * w + xi, xr1 = xr0 + 4;
    int xls0 = (xr0 >> 1) * 272 + (xr0 & 1) * 128 + xc * 8;
    int xls1 = (xr1 >> 1) * 272 + (xr1 & 1) * 128 + xc * 8;

    int mh = w & 1, nh = w >> 1;
    int r16 = l & 15;
    int q   = l >> 4;
    int ar = mh * 16 + r16;
    int br = nh * 16 + r16;
    const float*  wrow = &Ws[ar * 132];
    const __bf16* xrow = &Xs[(br >> 1) * 272 + (br & 1) * 128];

    f32x4 acc = {0.f, 0.f, 0.f, 0.f};

    // ---- slice A ----
    WAITN(6);                           // A's 6 done; B's 6 stay in flight
    *(f32x4*)&Ws[wls0] = Aw0; *(f32x4*)&Ws[wls1] = Aw1;
    *(f32x4*)&Ws[wls2] = Aw2; *(f32x4*)&Ws[wls3] = Aw3;
    *(f32x4*)((void*)&Xs[xls0]) = Ax0; *(f32x4*)((void*)&Xs[xls1]) = Ax1;
    __syncthreads();
    #pragma unroll
    for (int kk = 0; kk < 4; ++kk) {
        f32x4 a0 = *(const f32x4*)&wrow[kk * 32 + q * 8];
        f32x4 a1 = *(const f32x4*)&wrow[kk * 32 + q * 8 + 4];
        bf16x8 B = *(const bf16x8*)&xrow[(kk * 4 + q) * 8];
        acc = __builtin_amdgcn_mfma_f32_16x16x32_bf16(cvt8(a0, a1), B, acc, 0, 0, 0);
    }
    __syncthreads();

    // ---- slice B ----
    WAITN(0);
    *(f32x4*)&Ws[wls0] = Bw0; *(f32x4*)&Ws[wls1] = Bw1;
    *(f32x4*)&Ws[wls2] = Bw2; *(f32x4*)&Ws[wls3] = Bw3;
    *(f32x4*)((void*)&Xs[xls0]) = Bx0; *(f32x4*)((void*)&Xs[xls1]) = Bx1;
    __syncthreads();
    #pragma unroll
    for (int kk = 0; kk < 4; ++kk) {
        f32x4 a0 = *(const f32x4*)&wrow[kk * 32 + q * 8];
        f32x4 a1 = *(const f32x4*)&wrow[kk * 32 + q * 8 + 4];
        bf16x8 B = *(const bf16x8*)&xrow[(kk * 4 + q) * 8];
        acc = __builtin_amdgcn_mfma_f32_16x16x32_bf16(cvt8(a0, a1), B, acc, 0, 0, 0);
    }

    // C/D: col(batch) = l&15, row(d) = q*4 + j
    *(f32x4*)&C[(size_t)br * ldc + d0 + mh * 16 + q * 4] = acc;
}

// ---------------------------------------------------------------------------
// fp32 -> bf16 cast (for x).
// ---------------------------------------------------------------------------
__global__ __launch_bounds__(256) void cvtx(
    const float* __restrict__ in, __bf16* __restrict__ out)
{
    int i = (blockIdx.x * 256 + threadIdx.x) * 4;
    f32x4 v = *(const f32x4*)&in[i];
    bf16x4 o;
    o[0] = (__bf16)v[0]; o[1] = (__bf16)v[1]; o[2] = (__bf16)v[2]; o[3] = (__bf16)v[3];
    *(bf16x4*)&out[i] = o;
}

// ---------------------------------------------------------------------------
// Small-tile barrier GEMM (proven; K2 only: output D=192, fp32 X, 4 MB W).
// ---------------------------------------------------------------------------
__global__ __launch_bounds__(256) void gemm32(
    const float* __restrict__ W0, float* __restrict__ C0,
    const float* __restrict__ W1, float* __restrict__ C1,
    const float* __restrict__ X,
    int K, int ldc, int nm, int S, int ksteps, int cstride)
{
    __shared__ float Wb[2][32 * 64];
    __shared__ float Xb[2][32 * 64];

    int bid = blockIdx.x;
    int m = bid % nm;
    int rest = bid / nm;
    int s = rest % S;
    int mat = rest / S;
    const float* W = mat ? W1 : W0;
    float* C = (mat ? C1 : C0) + (size_t)s * cstride;

    int d0 = m * 32;
    int k0 = s * (K / S);

    int t  = threadIdx.x;
    int l  = t & 63;
    int wv = t >> 6;
    int lr = l >> 4;
    int lc = l & 15;

    int row0 = 8 * wv + lr;
    int row1 = row0 + 4;
    int ch0 = lc ^ (row0 & 7);
    int ch1 = lc ^ (row1 & 7);
    const float* ws0 = W + (size_t)(d0 + row0) * K + k0 + ch0 * 4;
    const float* ws1 = W + (size_t)(d0 + row1) * K + k0 + ch1 * 4;
    const float* xs0 = X + (size_t)row0 * K + k0 + ch0 * 4;
    const float* xs1 = X + (size_t)row1 * K + k0 + ch1 * 4;
    int R0 = 8 * wv * 64;
    int R1 = (8 * wv + 4) * 64;

#define STAGE(pb)  do {                                                              \
        __builtin_amdgcn_global_load_lds((const AS1 void*)ws0, (AS3 void*)&Wb[pb][R0], 16, 0, 0); \
        __builtin_amdgcn_global_load_lds((const AS1 void*)ws1, (AS3 void*)&Wb[pb][R1], 16, 0, 0); \
        __builtin_amdgcn_global_load_lds((const AS1 void*)xs0, (AS3 void*)&Xb[pb][R0], 16, 0, 0); \
        __builtin_amdgcn_global_load_lds((const AS1 void*)xs1, (AS3 void*)&Xb[pb][R1], 16, 0, 0); \
        ws0 += 64; ws1 += 64; xs0 += 64; xs1 += 64;                                  \
    } while (0)

    int mh = wv & 1, nh = wv >> 1;
    int r16 = l & 15;
    int arow = mh * 16 + r16;
    int brow = nh * 16 + r16;
    int c0 = (l >> 4) * 2;
    int wo0 = arow * 64 + ((c0    ) ^ (arow & 7)) * 4;
    int wo1 = arow * 64 + ((c0 + 1) ^ (arow & 7)) * 4;
    int wo2 = arow * 64 + ((c0 + 8) ^ (arow & 7)) * 4;
    int wo3 = arow * 64 + ((c0 + 9) ^ (arow & 7)) * 4;
    int xo0 = brow * 64 + ((c0    ) ^ (brow & 7)) * 4;
    int xo1 = brow * 64 + ((c0 + 1) ^ (brow & 7)) * 4;
    int xo2 = brow * 64 + ((c0 + 8) ^ (brow & 7)) * 4;
    int xo3 = brow * 64 + ((c0 + 9) ^ (brow & 7)) * 4;

    STAGE(0);
    STAGE(1);

    f32x4 acc = {0.f, 0.f, 0.f, 0.f};

    for (int it = 0; it < ksteps; ++it) {
        int c = it & 1;
        if (it < ksteps - 1) WAITN(4); else WAITN(0);
        __builtin_amdgcn_s_barrier();

        f32x4 a0 = *(const f32x4*)&Wb[c][wo0];
        f32x4 a1 = *(const f32x4*)&Wb[c][wo1];
        f32x4 a2 = *(const f32x4*)&Wb[c][wo2];
        f32x4 a3 = *(const f32x4*)&Wb[c][wo3];
        f32x4 b0 = *(const f32x4*)&Xb[c][xo0];
        f32x4 b1 = *(const f32x4*)&Xb[c][xo1];
        f32x4 b2 = *(const f32x4*)&Xb[c][xo2];
        f32x4 b3 = *(const f32x4*)&Xb[c][xo3];
        acc = __builtin_amdgcn_mfma_f32_16x16x32_bf16(cvt8(a0, a1), cvt8(b0, b1), acc, 0, 0, 0);
        acc = __builtin_amdgcn_mfma_f32_16x16x32_bf16(cvt8(a2, a3), cvt8(b2, b3), acc, 0, 0, 0);

        __builtin_amdgcn_s_barrier();
        if (it + 2 < ksteps) STAGE(c);
    }
#undef STAGE

    int b = brow;
    int dbase = d0 + mh * 16 + (l >> 4) * 4;
    *(f32x4*)&C[(size_t)b * ldc + dbase] = acc;
}

// ---------------------------------------------------------------------------
// Depthwise causal conv (k=4) + SiLU + reduce K1 split-K partials (S=10).
// ---------------------------------------------------------------------------
__global__ __launch_bounds__(256) void convk(
    const float* __restrict__ P_xs, const float* __restrict__ P_res,
    const float* __restrict__ conv_states,
    const float* __restrict__ conv_w, const float* __restrict__ conv_b,
    float* __restrict__ conv_bd, float* __restrict__ res_bd)
{
    const size_t BD = (size_t)BB * DI;
    int d = blockIdx.x * 256 + threadIdx.x;
    int b = blockIdx.y;
    size_t o = (size_t)b * DI + d;
    float xs = 0.f, rs = 0.f;
    #pragma unroll
    for (int j = 0; j < 10; ++j) {
        xs += P_xs[j * BD + o];
        rs += P_res[j * BD + o];
    }
    res_bd[o] = rs;
    float v = conv_states[(size_t)(1 * BB + b) * DI + d] * conv_w[0 * DI + d]
            + conv_states[(size_t)(2 * BB + b) * DI + d] * conv_w[1 * DI + d]
            + conv_states[(size_t)(3 * BB + b) * DI + d] * conv_w[2 * DI + d]
            + xs * conv_w[3 * DI + d] + conv_b[d];
    conv_bd[o] = v * sigmoidf_(v);
}

// ---------------------------------------------------------------------------
// Reduce K2 split-K partials.
// ---------------------------------------------------------------------------
__global__ __launch_bounds__(256) void redx(
    const float* __restrict__ p, float* __restrict__ o, int S)
{
    int i = blockIdx.x * 256 + threadIdx.x;
    float sum = 0.f;
    for (int s = 0; s < S; ++s) sum += p[(size_t)s * BB * NJ + i];
    o[i] = sum;
}

// ---------------------------------------------------------------------------
// Reduce K4 split-K partials (S=20) into d_out.
// ---------------------------------------------------------------------------
__global__ __launch_bounds__(256) void rout(
    const float* __restrict__ p, float* __restrict__ o)
{
    const int SZ = BB * DM;
    int i = blockIdx.x * 256 + threadIdx.x;
    float s = 0.f;
    #pragma unroll
    for (int j = 0; j < 20; ++j) s += p[(size_t)j * SZ + i];
    o[i] = s;
}

// ---------------------------------------------------------------------------
// Fused dt GEMV + softplus + SSM recurrence + D skip + SiLU gate -> g (bf16).
// ---------------------------------------------------------------------------
__global__ __launch_bounds__(256) void ssmk2(
    const float* __restrict__ x_db, const float* __restrict__ W_dt,
    const float* __restrict__ dt_bias, const float* __restrict__ A_log,
    const float* __restrict__ Dv, const float* __restrict__ ssm_state,
    const float* __restrict__ conv_bd, const float* __restrict__ res_bd,
    __bf16* __restrict__ g_bh)
{
    __shared__ float Wdt_s[8][164];
    __shared__ float xdb_s[BB][196];
    __shared__ float Al_s[8][NS];

    int t = threadIdx.x;
    int d0 = blockIdx.x * 8;

    for (int f = t; f < 8 * RK; f += 256)
        Wdt_s[f / RK][f % RK] = W_dt[(size_t)d0 * RK + f];
    for (int f = t; f < BB * NJ; f += 256)
        xdb_s[f / NJ][f % NJ] = x_db[f];
    if (t < 8 * NS)
        Al_s[t / NS][t % NS] = A_log[(size_t)(d0 + t / NS) * NS + t % NS];
    __syncthreads();

    int b  = t & 31;
    int dl = t >> 5;
    int d  = d0 + dl;

    float acc = 0.f;
    #pragma unroll 8
    for (int k4 = 0; k4 < RK / 4; ++k4) {
        f32x4 wv = *(const f32x4*)&Wdt_s[dl][k4 * 4];
        f32x4 xv = *(const f32x4*)&xdb_s[b][k4 * 4];
        acc += wv[0] * xv[0] + wv[1] * xv[1] + wv[2] * xv[2] + wv[3] * xv[3];
    }
    float dt = softplusf_(acc + dt_bias[d]);

    size_t off = (size_t)b * DI + d;
    float cv = conv_bd[off];
    float rv = res_bd[off];
    float Dd = Dv[d];

    const f32x4* sp = (const f32x4*)(ssm_state + off * NS);
    float y = 0.f;
    #pragma unroll
    for (int q = 0; q < 4; ++q) {
        f32x4 sv = sp[q];
        #pragma unroll
        for (int j = 0; j < 4; ++j) {
            int n = q * 4 + j;
            float dA = __expf(-dt * __expf(Al_s[dl][n]));
            y += (sv[j] * dA + dt * xdb_s[b][RK + n] * cv) * xdb_s[b][RK + NS + n];
        }
    }
    y += Dd * cv;
    g_bh[off] = (__bf16)(y * (rv * sigmoidf_(rv)));
}

// ---------------------------------------------------------------------------

extern "C" void kernel_launch(void* const* d_in, const int* in_sizes, int n_in,
                              void* d_out, int out_size, void* d_ws, size_t ws_size,
                              hipStream_t stream)
{
    const float* x           = (const float*)d_in[0];
    const float* conv_states = (const float*)d_in[1];
    const float* conv_w      = (const float*)d_in[2];
    const float* conv_b      = (const float*)d_in[3];
    const float* W_ssm_in    = (const float*)d_in[4];
    const float* W_mlp       = (const float*)d_in[5];
    const float* W_out       = (const float*)d_in[6];
    const float* W_x_proj    = (const float*)d_in[7];
    const float* W_dt        = (const float*)d_in[8];
    const float* dt_bias     = (const float*)d_in[9];
    const float* A_log       = (const float*)d_in[10];
    const float* Dv          = (const float*)d_in[11];
    const float* ssm_state   = (const float*)d_in[12];

    float* out = (float*)d_out;
    float* ws  = (float*)d_ws;

    const size_t BD = (size_t)BB * DI;          // 163840
    const int S1 = 10;                          // K1 split-K (gemmrs2, 256 k/block)
    const int S2 = 20;                          // K2 split-K (gemm32)
    const int S4 = 20;                          // K4 split-K (gemmrs2, 256 k/block)

    float* P_res   = ws;                        // 10*BD
    float* P_xs    = ws + (size_t)S1 * BD;      // 10*BD
    float* conv_bd = ws + 2 * (size_t)S1 * BD;
    float* res_bd  = conv_bd + BD;
    float* x_db_p  = res_bd + BD;               // S2*6144
    float* x_db    = x_db_p + (size_t)S2 * BB * NJ;
    __bf16* x_bh   = (__bf16*)(x_db + BB * NJ); // BB*DM bf16
    // aliases into the dead P region (after convk):
    float*  outp   = ws;                                    // S4*BB*DM floats
    __bf16* g_bh   = (__bf16*)(ws + (size_t)S4 * BB * DM);  // BD bf16

    // x -> bf16
    cvtx<<<dim3((BB * DM) / 1024), 256, 0, stream>>>(x, x_bh);

    // K1: res/xs partials (dual matrix): K=2560, 32d-tiles, 256 k/block, S=10
    gemmrs2<<<dim3((DI / 32) * S1 * 2), 256, 0, stream>>>(
        W_mlp, P_res, W_ssm_in, P_xs, x_bh, DM, DI, DI / 32, S1, (int)BD);

    // conv + silu + reduce K1 partials
    convk<<<dim3(DI / 256, BB), 256, 0, stream>>>(
        P_xs, P_res, conv_states, conv_w, conv_b, conv_bd, res_bd);

    // K2: x_db partials = conv @ W_x_proj.T  (K=5120, S=20, ksteps=4, BK=64)
    gemm32<<<dim3(6 * S2), 256, 0, stream>>>(
        W_x_proj, x_db_p, W_x_proj, x_db_p, conv_bd, DI, NJ, 6, S2, (DI / S2) / 64, BB * NJ);

    // reduce x_db partials
    redx<<<dim3((BB * NJ) / 256), 256, 0, stream>>>(x_db_p, x_db, S2);

    // fused dt + SSM + gate -> g (bf16)
    ssmk2<<<dim3(DI / 8), 256, 0, stream>>>(
        x_db, W_dt, dt_bias, A_log, Dv, ssm_state, conv_bd, res_bd, g_bh);

    // K4: out partials = g @ W_out.T  (K=5120, 32d-tiles, 256 k/block, S=20)
    gemmrs2<<<dim3((DM / 32) * S4), 256, 0, stream>>>(
        W_out, outp, W_out, outp, g_bh, DI, DM, DM / 32, S4, BB * DM);

    // final reduce into d_out
    rout<<<dim3((BB * DM) / 256), 256, 0, stream>>>(outp, out);
}